// Round 1
// baseline (350.945 us; speedup 1.0000x reference)
//
#include <hip/hip_runtime.h>
#include <stdint.h>

#define N_NODES 50000
#define N_EDGES 800000
#define SPAN_DIM 768
#define EMB_DIM 128
#define HID 256
#define N_TYPES 8
#define NKB (SPAN_DIM / 32)   // 24 k-blocks of 32
#define NNF (HID / 16)        // 16 n-frags of 16
#define NT_K (SPAN_DIM / 64)  // 12 K-steps of BK=64
#define M_PAD ((N_NODES + 63) & ~63)  // 50048
#define GEMM_BLOCKS (M_PAD / 64)      // 782

typedef unsigned short u16;
typedef u16 us8 __attribute__((ext_vector_type(8)));
typedef __bf16 bf16x8 __attribute__((ext_vector_type(8)));
typedef float f32x4 __attribute__((ext_vector_type(4)));

// fp32 -> bf16 round-to-nearest-even
__device__ __forceinline__ u16 f2bf(float f) {
  union { float f; uint32_t u; } v; v.f = f;
  uint32_t u = v.u;
  u += 0x7FFFu + ((u >> 16) & 1u);
  return (u16)(u >> 16);
}

// async global->LDS, 16B per lane; LDS dest is wave-uniform base + lane*16
__device__ __forceinline__ void gload16(const void* g, void* l) {
  __builtin_amdgcn_global_load_lds(
      (__attribute__((address_space(1))) void*)(uintptr_t)g,
      (__attribute__((address_space(3))) void*)l, 16, 0, 0);
}

// ---------------- T = node_emb @ W[768:896]  (8 x 256) ----------------
__global__ void tmat_kernel(const float* __restrict__ emb,
                            const float* __restrict__ W,
                            float* __restrict__ T) {
  int c = threadIdx.x;  // 256 threads, 1 block
  float acc[N_TYPES];
#pragma unroll
  for (int t = 0; t < N_TYPES; ++t) acc[t] = 0.f;
  for (int k = 0; k < EMB_DIM; ++k) {
    float wv = W[(size_t)(SPAN_DIM + k) * HID + c];
#pragma unroll
    for (int t = 0; t < N_TYPES; ++t)
      acc[t] = fmaf(emb[t * EMB_DIM + k], wv, acc[t]);
  }
#pragma unroll
  for (int t = 0; t < N_TYPES; ++t) T[(size_t)t * HID + c] = acc[t];
}

// ---------------- W[0:768] -> bf16 fragment-ordered pack ----------------
// wp[kb][nf][lane][j] = bf16( W[kb*32 + (lane>>4)*8 + j][nf*16 + (lane&15)] )
__global__ void wpack_kernel(const float* __restrict__ W, u16* __restrict__ wp) {
  int tid = blockIdx.x * 256 + threadIdx.x;  // 24*16*64 = 24576 threads
  int lane = tid & 63;
  int g = tid >> 6;            // kb*16 + nf, 0..383
  int nf = g & 15, kb = g >> 4;
  int k0 = kb * 32 + (lane >> 4) * 8;
  int col = nf * 16 + (lane & 15);
  us8 o;
#pragma unroll
  for (int j = 0; j < 8; ++j) o[j] = f2bf(W[(size_t)(k0 + j) * HID + col]);
  *(us8*)(wp + ((size_t)g * 64 + lane) * 8) = o;
}

// ---------------- degree count over dst ----------------
__global__ void count_kernel(const int* __restrict__ ei, int* __restrict__ cnt) {
  int e = blockIdx.x * 256 + threadIdx.x;
  if (e < N_EDGES) atomicAdd(&cnt[ei[N_EDGES + e]], 1);
}

// ---------------- single-block exclusive scan + dinv + cursor ----------------
__global__ __launch_bounds__(1024) void scan_kernel(const int* __restrict__ cnt,
                                                    int* __restrict__ offsets,
                                                    int* __restrict__ cursor,
                                                    float* __restrict__ dinv) {
  __shared__ int wsum[16];
  __shared__ int carry_s;
  const int tid = threadIdx.x, lane = tid & 63, wid = tid >> 6;
  if (tid == 0) carry_s = 0;
  __syncthreads();
  const int NCH = (N_NODES + 1023) / 1024;  // 49
  for (int ch = 0; ch < NCH; ++ch) {
    int i = ch * 1024 + tid;
    int v = (i < N_NODES) ? cnt[i] : 0;
    int s = v;
#pragma unroll
    for (int d = 1; d < 64; d <<= 1) {
      int t = __shfl_up(s, d, 64);
      if (lane >= d) s += t;
    }
    if (lane == 63) wsum[wid] = s;
    __syncthreads();
    if (tid < 16) {
      int t = wsum[tid];
#pragma unroll
      for (int d = 1; d < 16; d <<= 1) {
        int u = __shfl_up(t, d, 64);
        if (tid >= d) t += u;
      }
      wsum[tid] = t;  // inclusive sums of waves
    }
    __syncthreads();
    int wbase = (wid > 0) ? wsum[wid - 1] : 0;
    int base = carry_s;
    if (i < N_NODES) {
      int off = base + wbase + s - v;  // exclusive
      offsets[i] = off;
      cursor[i] = off;
      dinv[i] = rsqrtf((float)(v + 1));  // +1 self-loop
    }
    __syncthreads();
    if (tid == 0) carry_s = base + wsum[15];
    __syncthreads();
  }
  if (tid == 0) offsets[N_NODES] = carry_s;
}

// ---------------- CSR fill (order within bin nondeterministic; fp-rounding only) ----
__global__ void fill_kernel(const int* __restrict__ ei, int* __restrict__ cursor,
                            int* __restrict__ csr) {
  int e = blockIdx.x * 256 + threadIdx.x;
  if (e < N_EDGES) {
    int d = ei[N_EDGES + e];
    int pos = atomicAdd(&cursor[d], 1);
    csr[pos] = ei[e];
  }
}

// ---------------- h = span @ W_top + T[type]   (bf16 MFMA 16x16x32) ----------------
// block: 256 thr (4 waves), tile BM=64 x BN=256, BK=64, double-buffered LDS.
// LDS fragment-ordered: zero bank conflicts, linear global_load_lds for W.
__global__ __launch_bounds__(256, 2) void gemm_kernel(
    const float* __restrict__ span, const u16* __restrict__ wp,
    const float* __restrict__ T, const int* __restrict__ type_f,
    float* __restrict__ h) {
  __shared__ __align__(16) u16 Albs[2][8][64][8];    // [buf][rb*2+kb][lane][8]  16KB
  __shared__ __align__(16) u16 Blbs[2][32][64][8];   // [buf][kb*16+nf][lane][8] 64KB
  const int tid = threadIdx.x;
  const int lane = tid & 63;
  const int wv = tid >> 6;
  const int row0 = blockIdx.x * 64;

  f32x4 acc[4][4];
#pragma unroll
  for (int m = 0; m < 4; ++m)
#pragma unroll
    for (int n = 0; n < 4; ++n) acc[m][n] = (f32x4){0.f, 0.f, 0.f, 0.f};

  float4 areg[2][2];

  auto loadA = [&](int kt) {
#pragma unroll
    for (int i = 0; i < 2; ++i) {
      const int g = i * 4 + wv;
      const int rb = g >> 1, kb = g & 1;
      const int row = row0 + rb * 16 + (lane & 15);
      const int k0 = kt * 64 + kb * 32 + (lane >> 4) * 8;
      if (row < N_NODES) {
        const float* s = span + (size_t)row * SPAN_DIM + k0;
        areg[i][0] = *(const float4*)s;
        areg[i][1] = *(const float4*)(s + 4);
      } else {
        areg[i][0] = make_float4(0.f, 0.f, 0.f, 0.f);
        areg[i][1] = make_float4(0.f, 0.f, 0.f, 0.f);
      }
    }
  };
  auto writeA = [&](int buf) {
#pragma unroll
    for (int i = 0; i < 2; ++i) {
      const int g = i * 4 + wv;
      us8 o;
      o[0] = f2bf(areg[i][0].x); o[1] = f2bf(areg[i][0].y);
      o[2] = f2bf(areg[i][0].z); o[3] = f2bf(areg[i][0].w);
      o[4] = f2bf(areg[i][1].x); o[5] = f2bf(areg[i][1].y);
      o[6] = f2bf(areg[i][1].z); o[7] = f2bf(areg[i][1].w);
      *(us8*)&Albs[buf][g][lane][0] = o;
    }
  };
  auto stageB = [&](int buf, int kt) {
    const u16* wb = wp + (size_t)(kt * 2 * NNF) * 512;  // contiguous 32KB slice
#pragma unroll
    for (int i = 0; i < 8; ++i) {
      const int g = i * 4 + wv;
      gload16(wb + (size_t)g * 512 + (size_t)lane * 8, &Blbs[buf][g][0][0]);
    }
  };
  auto compute = [&](int buf) {
#pragma unroll
    for (int kb = 0; kb < 2; ++kb) {
      bf16x8 a[4], b[4];
#pragma unroll
      for (int m = 0; m < 4; ++m)
        a[m] = *(const bf16x8*)&Albs[buf][m * 2 + kb][lane][0];
#pragma unroll
      for (int n = 0; n < 4; ++n)
        b[n] = *(const bf16x8*)&Blbs[buf][kb * 16 + wv * 4 + n][lane][0];
#pragma unroll
      for (int m = 0; m < 4; ++m)
#pragma unroll
        for (int n = 0; n < 4; ++n)
          acc[m][n] =
              __builtin_amdgcn_mfma_f32_16x16x32_bf16(a[m], b[n], acc[m][n], 0, 0, 0);
    }
  };

  loadA(0);
  stageB(0, 0);
  writeA(0);
  __syncthreads();

  for (int kt = 0; kt < NT_K; ++kt) {
    const int cur = kt & 1, nxt = cur ^ 1;
    if (kt + 1 < NT_K) { loadA(kt + 1); stageB(nxt, kt + 1); }
    compute(cur);
    if (kt + 1 < NT_K) writeA(nxt);  // vmcnt-waits on areg under the MFMAs
    __syncthreads();
  }

  // epilogue: D row=(lane>>4)*4+reg, col=lane&15 (per 16x16 frag)
#pragma unroll
  for (int m = 0; m < 4; ++m) {
#pragma unroll
    for (int rg = 0; rg < 4; ++rg) {
      const int r = row0 + m * 16 + ((lane >> 4) << 2) + rg;
      if (r < N_NODES) {
        const int ty = type_f[r];
        const float* Tr = T + (size_t)ty * HID;
#pragma unroll
        for (int n = 0; n < 4; ++n) {
          const int c = wv * 64 + n * 16 + (lane & 15);
          h[(size_t)r * HID + c] = acc[m][n][rg] + Tr[c];
        }
      }
    }
  }
}

// ---------------- aggregate: one wave per node, float4 per lane ----------------
__global__ __launch_bounds__(256) void agg_kernel(
    const float* __restrict__ h, const int* __restrict__ csr,
    const int* __restrict__ offsets, const float* __restrict__ dinv,
    const float* __restrict__ bias, const float* __restrict__ alpha,
    float* __restrict__ out) {
  const int lane = threadIdx.x & 63;
  const int node = blockIdx.x * 4 + (threadIdx.x >> 6);
  if (node >= N_NODES) return;
  const float di = dinv[node];
  const float4* __restrict__ h4 = (const float4*)h;
  float4 v = h4[(size_t)node * 64 + lane];
  float4 acc;
  acc.x = di * v.x; acc.y = di * v.y; acc.z = di * v.z; acc.w = di * v.w;
  const int beg = offsets[node], end = offsets[node + 1];
  int j = beg;
  for (; j + 1 < end; j += 2) {
    int s0 = csr[j], s1 = csr[j + 1];
    float w0 = dinv[s0], w1 = dinv[s1];
    float4 v0 = h4[(size_t)s0 * 64 + lane];
    float4 v1 = h4[(size_t)s1 * 64 + lane];
    acc.x = fmaf(w0, v0.x, acc.x); acc.y = fmaf(w0, v0.y, acc.y);
    acc.z = fmaf(w0, v0.z, acc.z); acc.w = fmaf(w0, v0.w, acc.w);
    acc.x = fmaf(w1, v1.x, acc.x); acc.y = fmaf(w1, v1.y, acc.y);
    acc.z = fmaf(w1, v1.z, acc.z); acc.w = fmaf(w1, v1.w, acc.w);
  }
  if (j < end) {
    int s0 = csr[j];
    float w0 = dinv[s0];
    float4 v0 = h4[(size_t)s0 * 64 + lane];
    acc.x = fmaf(w0, v0.x, acc.x); acc.y = fmaf(w0, v0.y, acc.y);
    acc.z = fmaf(w0, v0.z, acc.z); acc.w = fmaf(w0, v0.w, acc.w);
  }
  float4 bb = ((const float4*)bias)[lane];
  float4 aa = ((const float4*)alpha)[lane];
  float4 r;
  r.x = fmaf(di, acc.x, bb.x); r.y = fmaf(di, acc.y, bb.y);
  r.z = fmaf(di, acc.z, bb.z); r.w = fmaf(di, acc.w, bb.w);
  r.x = r.x > 0.f ? r.x : aa.x * r.x;
  r.y = r.y > 0.f ? r.y : aa.y * r.y;
  r.z = r.z > 0.f ? r.z : aa.z * r.z;
  r.w = r.w > 0.f ? r.w : aa.w * r.w;
  ((float4*)out)[(size_t)node * 64 + lane] = r;
}

extern "C" void kernel_launch(void* const* d_in, const int* in_sizes, int n_in,
                              void* d_out, int out_size, void* d_ws, size_t ws_size,
                              hipStream_t stream) {
  const float* span = (const float*)d_in[0];
  const int* type_f = (const int*)d_in[1];
  const int* ei = (const int*)d_in[2];
  const float* emb = (const float*)d_in[3];
  const float* W = (const float*)d_in[4];
  const float* bias = (const float*)d_in[5];
  const float* alpha = (const float*)d_in[6];
  float* out = (float*)d_out;

  char* ws = (char*)d_ws;
  size_t off = 0;
  auto alloc = [&](size_t bytes) {
    char* p = ws + off;
    off = (off + bytes + 255) & ~(size_t)255;
    return p;
  };
  float* h = (float*)alloc((size_t)N_NODES * HID * 4);          // 51.2 MB
  u16* wp = (u16*)alloc((size_t)NKB * NNF * 64 * 8 * 2);        // 393 KB
  float* T = (float*)alloc((size_t)N_TYPES * HID * 4);          // 8 KB
  int* cnt = (int*)alloc((size_t)N_NODES * 4);
  int* offsets = (int*)alloc((size_t)(N_NODES + 1) * 4);
  int* cursor = (int*)alloc((size_t)N_NODES * 4);
  float* dinv = (float*)alloc((size_t)N_NODES * 4);
  int* csr = (int*)alloc((size_t)N_EDGES * 4);                  // 3.2 MB

  hipMemsetAsync(cnt, 0, (size_t)N_NODES * 4, stream);
  tmat_kernel<<<1, 256, 0, stream>>>(emb, W, T);
  wpack_kernel<<<96, 256, 0, stream>>>(W, wp);
  count_kernel<<<N_EDGES / 256, 256, 0, stream>>>(ei, cnt);
  scan_kernel<<<1, 1024, 0, stream>>>(cnt, offsets, cursor, dinv);
  fill_kernel<<<N_EDGES / 256, 256, 0, stream>>>(ei, cursor, csr);
  gemm_kernel<<<GEMM_BLOCKS, 256, 0, stream>>>(span, wp, T, type_f, h);
  agg_kernel<<<(N_NODES + 3) / 4, 256, 0, stream>>>(h, csr, offsets, dinv, bias,
                                                    alpha, out);
}

// Round 2
// 227.104 us; speedup vs baseline: 1.5453x; 1.5453x over previous
//
#include <hip/hip_runtime.h>
#include <stdint.h>

#define N_NODES 50000
#define N_EDGES 800000
#define SPAN_DIM 768
#define EMB_DIM 128
#define HID 256
#define N_TYPES 8
#define NKB (SPAN_DIM / 32)   // 24 k-blocks of 32
#define NNF (HID / 16)        // 16 n-frags of 16
#define NT_K (SPAN_DIM / 64)  // 12 K-steps of BK=64
#define M_PAD ((N_NODES + 63) & ~63)  // 50048
#define GEMM_BLOCKS (M_PAD / 64)      // 782
#define NRB ((N_NODES + 255) / 256)   // 196 scan blocks

typedef unsigned short u16;
typedef u16 us8 __attribute__((ext_vector_type(8)));
typedef u16 us4 __attribute__((ext_vector_type(4)));
typedef __bf16 bf16x8 __attribute__((ext_vector_type(8)));
typedef float f32x4 __attribute__((ext_vector_type(4)));

// fp32 -> bf16 round-to-nearest-even
__device__ __forceinline__ u16 f2bf(float f) {
  union { float f; uint32_t u; } v; v.f = f;
  uint32_t u = v.u;
  u += 0x7FFFu + ((u >> 16) & 1u);
  return (u16)(u >> 16);
}
__device__ __forceinline__ float bf2f(u16 x) {
  union { uint32_t u; float f; } v; v.u = ((uint32_t)x) << 16;
  return v.f;
}

// async global->LDS, 16B per lane; LDS dest is wave-uniform base + lane*16
__device__ __forceinline__ void gload16(const void* g, void* l) {
  __builtin_amdgcn_global_load_lds(
      (__attribute__((address_space(1))) void*)(uintptr_t)g,
      (__attribute__((address_space(3))) void*)l, 16, 0, 0);
}

// ------------- fused prep: W[0:768] bf16 pack (blocks 0..95) + T (96..103) ----
// wp[kb][nf][lane][j] = bf16( W[kb*32 + (lane>>4)*8 + j][nf*16 + (lane&15)] )
__global__ void prep_kernel(const float* __restrict__ emb,
                            const float* __restrict__ W,
                            u16* __restrict__ wp, float* __restrict__ T) {
  if (blockIdx.x < 96) {
    int tid = blockIdx.x * 256 + threadIdx.x;
    int lane = tid & 63;
    int g = tid >> 6;  // kb*16 + nf, 0..383
    int nf = g & 15, kb = g >> 4;
    int k0 = kb * 32 + (lane >> 4) * 8;
    int col = nf * 16 + (lane & 15);
    us8 o;
#pragma unroll
    for (int j = 0; j < 8; ++j) o[j] = f2bf(W[(size_t)(k0 + j) * HID + col]);
    *(us8*)(wp + ((size_t)g * 64 + lane) * 8) = o;
  } else {
    int t = blockIdx.x - 96;  // 0..7
    int c = threadIdx.x;
    float a = 0.f;
    for (int k = 0; k < EMB_DIM; ++k)
      a = fmaf(emb[t * EMB_DIM + k], W[(size_t)(SPAN_DIM + k) * HID + c], a);
    T[(size_t)t * HID + c] = a;
  }
}

// ---------------- degree count over dst ----------------
__global__ void count_kernel(const int* __restrict__ ei, int* __restrict__ cnt) {
  int e = blockIdx.x * 256 + threadIdx.x;
  if (e < N_EDGES) atomicAdd(&cnt[ei[N_EDGES + e]], 1);
}

// ---------------- scan phase 1: per-block sums + dinv ----------------
__global__ void reduce_kernel(const int* __restrict__ cnt, int* __restrict__ bsum,
                              float* __restrict__ dinv) {
  __shared__ int ws[4];
  const int tid = threadIdx.x, lane = tid & 63, wid = tid >> 6;
  const int i = blockIdx.x * 256 + tid;
  int v = (i < N_NODES) ? cnt[i] : 0;
  if (i < N_NODES) dinv[i] = rsqrtf((float)(v + 1));
  int s = v;
#pragma unroll
  for (int d = 32; d; d >>= 1) s += __shfl_down(s, d, 64);
  if (lane == 0) ws[wid] = s;
  __syncthreads();
  if (tid == 0) bsum[blockIdx.x] = ws[0] + ws[1] + ws[2] + ws[3];
}

// ---------------- scan phase 2: 1 wave scans 196 block sums (in place) -------
__global__ void scanb_kernel(int* __restrict__ bsum, int* __restrict__ offsets) {
  const int lane = threadIdx.x;  // 64 threads
  int v[4];
  int s = 0;
#pragma unroll
  for (int k = 0; k < 4; ++k) {
    int idx = lane * 4 + k;
    v[k] = (idx < NRB) ? bsum[idx] : 0;
    s += v[k];
  }
  int incl = s;
#pragma unroll
  for (int d = 1; d < 64; d <<= 1) {
    int t = __shfl_up(incl, d, 64);
    if (lane >= d) incl += t;
  }
  int base = incl - s;  // exclusive base for this lane's range
#pragma unroll
  for (int k = 0; k < 4; ++k) {
    int idx = lane * 4 + k;
    if (idx < NRB) { bsum[idx] = base; base += v[k]; }
  }
  if (lane == 63) offsets[N_NODES] = incl;  // grand total
}

// ---------------- scan phase 3: block-local exclusive scan ----------------
__global__ void scanc_kernel(const int* __restrict__ cnt, const int* __restrict__ bsum,
                             int* __restrict__ offsets, int* __restrict__ cursor) {
  __shared__ int ws[4];
  const int tid = threadIdx.x, lane = tid & 63, wid = tid >> 6;
  const int i = blockIdx.x * 256 + tid;
  int v = (i < N_NODES) ? cnt[i] : 0;
  int s = v;
#pragma unroll
  for (int d = 1; d < 64; d <<= 1) {
    int t = __shfl_up(s, d, 64);
    if (lane >= d) s += t;
  }
  if (lane == 63) ws[wid] = s;
  __syncthreads();
  int wbase = 0;
#pragma unroll
  for (int w = 0; w < 4; ++w) wbase += (w < wid) ? ws[w] : 0;
  if (i < N_NODES) {
    int off = bsum[blockIdx.x] + wbase + s - v;
    offsets[i] = off;
    cursor[i] = off;
  }
}

// ---------------- CSR fill ----------------
__global__ void fill_kernel(const int* __restrict__ ei, int* __restrict__ cursor,
                            int* __restrict__ csr) {
  int e = blockIdx.x * 256 + threadIdx.x;
  if (e < N_EDGES) {
    int d = ei[N_EDGES + e];
    int pos = atomicAdd(&cursor[d], 1);
    csr[pos] = ei[e];
  }
}

// ---------------- h = span @ W_top + T[type]   (bf16 MFMA 16x16x32) ----------
// h stored bf16, PERMUTED channel order: storage slot B*64+p*4+q holds true
// channel B*64+q*16+p  (B=0..3, p=0..15, q=0..3).
__global__ __launch_bounds__(256, 2) void gemm_kernel(
    const float* __restrict__ span, const u16* __restrict__ wp,
    const float* __restrict__ T, const int* __restrict__ type_f,
    u16* __restrict__ h) {
  __shared__ __align__(16) u16 Albs[2][8][64][8];    // 16KB
  __shared__ __align__(16) u16 Blbs[2][32][64][8];   // 64KB
  const int tid = threadIdx.x;
  const int lane = tid & 63;
  const int wv = tid >> 6;
  const int row0 = blockIdx.x * 64;

  f32x4 acc[4][4];
#pragma unroll
  for (int m = 0; m < 4; ++m)
#pragma unroll
    for (int n = 0; n < 4; ++n) acc[m][n] = (f32x4){0.f, 0.f, 0.f, 0.f};

  float4 areg[2][2];

  auto loadA = [&](int kt) {
#pragma unroll
    for (int i = 0; i < 2; ++i) {
      const int g = i * 4 + wv;
      const int rb = g >> 1, kb = g & 1;
      const int row = row0 + rb * 16 + (lane & 15);
      const int k0 = kt * 64 + kb * 32 + (lane >> 4) * 8;
      if (row < N_NODES) {
        const float* s = span + (size_t)row * SPAN_DIM + k0;
        areg[i][0] = *(const float4*)s;
        areg[i][1] = *(const float4*)(s + 4);
      } else {
        areg[i][0] = make_float4(0.f, 0.f, 0.f, 0.f);
        areg[i][1] = make_float4(0.f, 0.f, 0.f, 0.f);
      }
    }
  };
  auto writeA = [&](int buf) {
#pragma unroll
    for (int i = 0; i < 2; ++i) {
      const int g = i * 4 + wv;
      us8 o;
      o[0] = f2bf(areg[i][0].x); o[1] = f2bf(areg[i][0].y);
      o[2] = f2bf(areg[i][0].z); o[3] = f2bf(areg[i][0].w);
      o[4] = f2bf(areg[i][1].x); o[5] = f2bf(areg[i][1].y);
      o[6] = f2bf(areg[i][1].z); o[7] = f2bf(areg[i][1].w);
      *(us8*)&Albs[buf][g][lane][0] = o;
    }
  };
  auto stageB = [&](int buf, int kt) {
    const u16* wb = wp + (size_t)(kt * 2 * NNF) * 512;
#pragma unroll
    for (int i = 0; i < 8; ++i) {
      const int g = i * 4 + wv;
      gload16(wb + (size_t)g * 512 + (size_t)lane * 8, &Blbs[buf][g][0][0]);
    }
  };
  auto compute = [&](int buf) {
#pragma unroll
    for (int kb = 0; kb < 2; ++kb) {
      bf16x8 a[4], b[4];
#pragma unroll
      for (int m = 0; m < 4; ++m)
        a[m] = *(const bf16x8*)&Albs[buf][m * 2 + kb][lane][0];
#pragma unroll
      for (int n = 0; n < 4; ++n)
        b[n] = *(const bf16x8*)&Blbs[buf][kb * 16 + wv * 4 + n][lane][0];
#pragma unroll
      for (int m = 0; m < 4; ++m)
#pragma unroll
        for (int n = 0; n < 4; ++n)
          acc[m][n] =
              __builtin_amdgcn_mfma_f32_16x16x32_bf16(a[m], b[n], acc[m][n], 0, 0, 0);
    }
  };

  loadA(0);
  stageB(0, 0);
  writeA(0);
  __syncthreads();

  for (int kt = 0; kt < NT_K; ++kt) {
    const int cur = kt & 1, nxt = cur ^ 1;
    if (kt + 1 < NT_K) { loadA(kt + 1); stageB(nxt, kt + 1); }
    compute(cur);
    if (kt + 1 < NT_K) writeA(nxt);
    __syncthreads();
  }

  // epilogue: D row=(lane>>4)*4+rg, col(lane frag)=lane&15; pack 4 n-values
  // into one us4 store at permuted slot wv*64 + (lane&15)*4.
#pragma unroll
  for (int m = 0; m < 4; ++m) {
#pragma unroll
    for (int rg = 0; rg < 4; ++rg) {
      const int r = row0 + m * 16 + ((lane >> 4) << 2) + rg;
      if (r < N_NODES) {
        const int ty = type_f[r];
        const float* Tr = T + (size_t)ty * HID;
        us4 o;
#pragma unroll
        for (int n = 0; n < 4; ++n) {
          const int c = wv * 64 + n * 16 + (lane & 15);
          o[n] = f2bf(acc[m][n][rg] + Tr[c]);
        }
        *(us4*)(h + (size_t)r * HID + wv * 64 + (lane & 15) * 4) = o;
      }
    }
  }
}

// ---------------- aggregate: one wave per node, us4 (8B) per lane ------------
__global__ __launch_bounds__(256) void agg_kernel(
    const u16* __restrict__ h, const int* __restrict__ csr,
    const int* __restrict__ offsets, const float* __restrict__ dinv,
    const float* __restrict__ bias, const float* __restrict__ alpha,
    float* __restrict__ out) {
  const int lane = threadIdx.x & 63;
  const int node = blockIdx.x * 4 + (threadIdx.x >> 6);
  if (node >= N_NODES) return;
  const int blk = lane >> 4, p = lane & 15;
  // storage slot lane*4+q holds true channel blk*64 + q*16 + p
  float bb[4], aa[4];
#pragma unroll
  for (int q = 0; q < 4; ++q) {
    const int c = blk * 64 + q * 16 + p;
    bb[q] = bias[c];
    aa[q] = alpha[c];
  }
  const us4* __restrict__ h4 = (const us4*)h;
  const float di = dinv[node];
  us4 v = h4[(size_t)node * 64 + lane];
  float acc[4];
#pragma unroll
  for (int q = 0; q < 4; ++q) acc[q] = di * bf2f(v[q]);
  const int beg = offsets[node], end = offsets[node + 1];
  int j = beg;
  for (; j + 3 < end; j += 4) {
    const int s0 = csr[j], s1 = csr[j + 1], s2 = csr[j + 2], s3 = csr[j + 3];
    const float w0 = dinv[s0], w1 = dinv[s1], w2 = dinv[s2], w3 = dinv[s3];
    const us4 v0 = h4[(size_t)s0 * 64 + lane];
    const us4 v1 = h4[(size_t)s1 * 64 + lane];
    const us4 v2 = h4[(size_t)s2 * 64 + lane];
    const us4 v3 = h4[(size_t)s3 * 64 + lane];
#pragma unroll
    for (int q = 0; q < 4; ++q) {
      acc[q] = fmaf(w0, bf2f(v0[q]), acc[q]);
      acc[q] = fmaf(w1, bf2f(v1[q]), acc[q]);
      acc[q] = fmaf(w2, bf2f(v2[q]), acc[q]);
      acc[q] = fmaf(w3, bf2f(v3[q]), acc[q]);
    }
  }
  for (; j < end; ++j) {
    const int s0 = csr[j];
    const float w0 = dinv[s0];
    const us4 v0 = h4[(size_t)s0 * 64 + lane];
#pragma unroll
    for (int q = 0; q < 4; ++q) acc[q] = fmaf(w0, bf2f(v0[q]), acc[q]);
  }
#pragma unroll
  for (int q = 0; q < 4; ++q) {
    float r = fmaf(di, acc[q], bb[q]);
    r = r > 0.f ? r : aa[q] * r;
    out[(size_t)node * HID + blk * 64 + q * 16 + p] = r;
  }
}

extern "C" void kernel_launch(void* const* d_in, const int* in_sizes, int n_in,
                              void* d_out, int out_size, void* d_ws, size_t ws_size,
                              hipStream_t stream) {
  const float* span = (const float*)d_in[0];
  const int* type_f = (const int*)d_in[1];
  const int* ei = (const int*)d_in[2];
  const float* emb = (const float*)d_in[3];
  const float* W = (const float*)d_in[4];
  const float* bias = (const float*)d_in[5];
  const float* alpha = (const float*)d_in[6];
  float* out = (float*)d_out;

  char* ws = (char*)d_ws;
  size_t off = 0;
  auto alloc = [&](size_t bytes) {
    char* p = ws + off;
    off = (off + bytes + 255) & ~(size_t)255;
    return p;
  };
  u16* h = (u16*)alloc((size_t)N_NODES * HID * 2);              // 25.6 MB (bf16)
  u16* wp = (u16*)alloc((size_t)NKB * NNF * 64 * 8 * 2);        // 393 KB
  float* T = (float*)alloc((size_t)N_TYPES * HID * 4);          // 8 KB
  int* cnt = (int*)alloc((size_t)N_NODES * 4);
  int* offsets = (int*)alloc((size_t)(N_NODES + 1) * 4);
  int* cursor = (int*)alloc((size_t)N_NODES * 4);
  float* dinv = (float*)alloc((size_t)N_NODES * 4);
  int* bsum = (int*)alloc((size_t)NRB * 4);
  int* csr = (int*)alloc((size_t)N_EDGES * 4);                  // 3.2 MB

  hipMemsetAsync(cnt, 0, (size_t)N_NODES * 4, stream);
  prep_kernel<<<104, 256, 0, stream>>>(emb, W, wp, T);
  count_kernel<<<N_EDGES / 256, 256, 0, stream>>>(ei, cnt);
  reduce_kernel<<<NRB, 256, 0, stream>>>(cnt, bsum, dinv);
  scanb_kernel<<<1, 64, 0, stream>>>(bsum, offsets);
  scanc_kernel<<<NRB, 256, 0, stream>>>(cnt, bsum, offsets, cursor);
  fill_kernel<<<N_EDGES / 256, 256, 0, stream>>>(ei, cursor, csr);
  gemm_kernel<<<GEMM_BLOCKS, 256, 0, stream>>>(span, wp, T, type_f, h);
  agg_kernel<<<(N_NODES + 3) / 4, 256, 0, stream>>>(h, csr, offsets, dinv, bias,
                                                    alpha, out);
}

// Round 4
// 207.460 us; speedup vs baseline: 1.6916x; 1.0947x over previous
//
#include <hip/hip_runtime.h>
#include <stdint.h>

#define N_NODES 50000
#define N_EDGES 800000
#define SPAN_DIM 768
#define EMB_DIM 128
#define HID 256
#define N_TYPES 8
#define NKB (SPAN_DIM / 32)   // 24 k-blocks of 32
#define NNF (HID / 16)        // 16 n-frags of 16
#define N_TILES (N_NODES / 16)        // 3125 exact
#define NRB ((N_NODES + 255) / 256)   // 196 scan blocks

typedef unsigned short u16;
typedef u16 us8 __attribute__((ext_vector_type(8)));
typedef u16 us4 __attribute__((ext_vector_type(4)));
typedef __bf16 bf16x8 __attribute__((ext_vector_type(8)));
typedef float f32x4 __attribute__((ext_vector_type(4)));

// fp32 -> bf16 round-to-nearest-even (bit-exact RNE)
__device__ __forceinline__ u16 f2bf(float f) {
  union { float f; uint32_t u; } v; v.f = f;
  uint32_t u = v.u;
  u += 0x7FFFu + ((u >> 16) & 1u);
  return (u16)(u >> 16);
}
__device__ __forceinline__ float bf2f(u16 x) {
  union { uint32_t u; float f; } v; v.u = ((uint32_t)x) << 16;
  return v.f;
}

// native packed cvt path (v_cvt_pk_bf16_f32, RNE)
__device__ __forceinline__ bf16x8 cvt8(float4 a, float4 b) {
  bf16x8 r;
  r[0] = (__bf16)a.x; r[1] = (__bf16)a.y; r[2] = (__bf16)a.z; r[3] = (__bf16)a.w;
  r[4] = (__bf16)b.x; r[5] = (__bf16)b.y; r[6] = (__bf16)b.z; r[7] = (__bf16)b.w;
  return r;
}

// async global->LDS, 16B per lane; GLOBAL src is PER-LANE, LDS dest is
// wave-uniform base + lane*16.
__device__ __forceinline__ void gload16(const void* g, void* l) {
  __builtin_amdgcn_global_load_lds(
      (__attribute__((address_space(1))) void*)(uintptr_t)g,
      (__attribute__((address_space(3))) void*)l, 16, 0, 0);
}

// ------------- fused prep: W[0:768] bf16 pack (blocks 0..95) + T (96..103) ----
// wp[kb][nf][lane][j] = bf16( W[kb*32 + (lane>>4)*8 + j][nf*16 + (lane&15)] )
__global__ void prep_kernel(const float* __restrict__ emb,
                            const float* __restrict__ W,
                            u16* __restrict__ wp, float* __restrict__ T) {
  if (blockIdx.x < 96) {
    int tid = blockIdx.x * 256 + threadIdx.x;
    int lane = tid & 63;
    int g = tid >> 6;  // kb*16 + nf, 0..383
    int nf = g & 15, kb = g >> 4;
    int k0 = kb * 32 + (lane >> 4) * 8;
    int col = nf * 16 + (lane & 15);
    us8 o;
#pragma unroll
    for (int j = 0; j < 8; ++j) o[j] = f2bf(W[(size_t)(k0 + j) * HID + col]);
    *(us8*)(wp + ((size_t)g * 64 + lane) * 8) = o;
  } else {
    int t = blockIdx.x - 96;  // 0..7
    int c = threadIdx.x;
    float a = 0.f;
    for (int k = 0; k < EMB_DIM; ++k)
      a = fmaf(emb[t * EMB_DIM + k], W[(size_t)(SPAN_DIM + k) * HID + c], a);
    T[(size_t)t * HID + c] = a;
  }
}

// ---------------- degree count over dst ----------------
__global__ void count_kernel(const int* __restrict__ ei, int* __restrict__ cnt) {
  int e = blockIdx.x * 256 + threadIdx.x;
  if (e < N_EDGES) atomicAdd(&cnt[ei[N_EDGES + e]], 1);
}

// ---------------- scan phase 1: per-block sums + dinv ----------------
__global__ void reduce_kernel(const int* __restrict__ cnt, int* __restrict__ bsum,
                              float* __restrict__ dinv) {
  __shared__ int ws[4];
  const int tid = threadIdx.x, lane = tid & 63, wid = tid >> 6;
  const int i = blockIdx.x * 256 + tid;
  int v = (i < N_NODES) ? cnt[i] : 0;
  if (i < N_NODES) dinv[i] = rsqrtf((float)(v + 1));
  int s = v;
#pragma unroll
  for (int d = 32; d; d >>= 1) s += __shfl_down(s, d, 64);
  if (lane == 0) ws[wid] = s;
  __syncthreads();
  if (tid == 0) bsum[blockIdx.x] = ws[0] + ws[1] + ws[2] + ws[3];
}

// ---------------- scan phase 2: 1 wave scans 196 block sums (in place) -------
__global__ void scanb_kernel(int* __restrict__ bsum, int* __restrict__ offsets) {
  const int lane = threadIdx.x;  // 64 threads
  int v[4];
  int s = 0;
#pragma unroll
  for (int k = 0; k < 4; ++k) {
    int idx = lane * 4 + k;
    v[k] = (idx < NRB) ? bsum[idx] : 0;
    s += v[k];
  }
  int incl = s;
#pragma unroll
  for (int d = 1; d < 64; d <<= 1) {
    int t = __shfl_up(incl, d, 64);
    if (lane >= d) incl += t;
  }
  int base = incl - s;  // exclusive base for this lane's range
#pragma unroll
  for (int k = 0; k < 4; ++k) {
    int idx = lane * 4 + k;
    if (idx < NRB) { bsum[idx] = base; base += v[k]; }
  }
  if (lane == 63) offsets[N_NODES] = incl;  // grand total
}

// ---------------- scan phase 3: block-local exclusive scan ----------------
__global__ void scanc_kernel(const int* __restrict__ cnt, const int* __restrict__ bsum,
                             int* __restrict__ offsets, int* __restrict__ cursor) {
  __shared__ int ws[4];
  const int tid = threadIdx.x, lane = tid & 63, wid = tid >> 6;
  const int i = blockIdx.x * 256 + tid;
  int v = (i < N_NODES) ? cnt[i] : 0;
  int s = v;
#pragma unroll
  for (int d = 1; d < 64; d <<= 1) {
    int t = __shfl_up(s, d, 64);
    if (lane >= d) s += t;
  }
  if (lane == 63) ws[wid] = s;
  __syncthreads();
  int wbase = 0;
#pragma unroll
  for (int w = 0; w < 4; ++w) wbase += (w < wid) ? ws[w] : 0;
  if (i < N_NODES) {
    int off = bsum[blockIdx.x] + wbase + s - v;
    offsets[i] = off;
    cursor[i] = off;
  }
}

// ---------------- CSR fill ----------------
__global__ void fill_kernel(const int* __restrict__ ei, int* __restrict__ cursor,
                            int* __restrict__ csr) {
  int e = blockIdx.x * 256 + threadIdx.x;
  if (e < N_EDGES) {
    int d = ei[N_EDGES + e];
    int pos = atomicAdd(&cursor[d], 1);
    csr[pos] = ei[e];
  }
}

// ---------------- h = span @ W_top + T[type]   (bf16 MFMA 16x16x32) ----------
// One wave owns 16 rows x full N=256 (16 n-frags). A: global->reg directly.
// B: 4 K-quarters (6 kb each) staged in 98KB LDS, 2 barriers per quarter.
// Block b owns 12-13 contiguous 16-row tiles; wave wv takes tiles wv and wv+8.
// h stored bf16, PERMUTED: slot g*64+p*4+q holds channel g*64+q*16+p (p=lane&15).
__global__ __launch_bounds__(512, 2) void gemm_kernel(
    const float* __restrict__ span, const u16* __restrict__ wp,
    const float* __restrict__ T, const int* __restrict__ type_f,
    u16* __restrict__ h) {
  __shared__ __align__(16) u16 Blds[96 * 512];  // 98304 B
  const int tid = threadIdx.x;
  const int lane = tid & 63;
  const int wv = tid >> 6;
  const int b = blockIdx.x;
  const int cntb = 12 + (b < 53 ? 1 : 0);            // 53*13 + 203*12 = 3125
  const int start = b * 12 + (b < 53 ? b : 53);
  const int t0 = start + wv;
  const bool has1 = (8 + wv) < cntb;
  const int t1 = start + 8 + wv;

  const int p = lane & 15, ko = (lane >> 4) * 8;
  const float* pA0 = span + (size_t)(t0 * 16 + p) * SPAN_DIM + ko;
  const float* pA1 = span + (size_t)(has1 ? t1 : t0) * 16 * SPAN_DIM +
                     (size_t)p * SPAN_DIM + ko;

  f32x4 acc[2][16];
#pragma unroll
  for (int s = 0; s < 2; ++s)
#pragma unroll
    for (int nf = 0; nf < 16; ++nf) acc[s][nf] = (f32x4){0.f, 0.f, 0.f, 0.f};

  for (int kq = 0; kq < 4; ++kq) {
    if (kq) __syncthreads();  // all waves done reading previous quarter
#pragma unroll
    for (int i = 0; i < 12; ++i) {
      const int sl = wv * 12 + i;
      gload16(wp + (size_t)(kq * 96 + sl) * 512 + (size_t)lane * 8,
              Blds + (size_t)sl * 512);
    }
    __syncthreads();  // staging complete (vmcnt drained by compiler)

    const float* q0 = pA0 + kq * 192;
    const float* q1 = pA1 + kq * 192;
    float4 c0a = *(const float4*)q0;
    float4 c0b = *(const float4*)(q0 + 4);
    float4 c1a = make_float4(0.f, 0.f, 0.f, 0.f), c1b = c1a;
    if (has1) { c1a = *(const float4*)q1; c1b = *(const float4*)(q1 + 4); }
#pragma unroll
    for (int kb = 0; kb < 6; ++kb) {
      float4 n0a = c0a, n0b = c0b, n1a = c1a, n1b = c1b;
      if (kb < 5) {
        n0a = *(const float4*)(q0 + (kb + 1) * 32);
        n0b = *(const float4*)(q0 + (kb + 1) * 32 + 4);
        if (has1) {
          n1a = *(const float4*)(q1 + (kb + 1) * 32);
          n1b = *(const float4*)(q1 + (kb + 1) * 32 + 4);
        }
      }
      bf16x8 a0 = cvt8(c0a, c0b);
      bf16x8 a1 = cvt8(c1a, c1b);
#pragma unroll
      for (int nf = 0; nf < 16; ++nf) {
        bf16x8 bb = *(const bf16x8*)&Blds[((kb * 16 + nf) * 64 + lane) * 8];
        acc[0][nf] =
            __builtin_amdgcn_mfma_f32_16x16x32_bf16(a0, bb, acc[0][nf], 0, 0, 0);
        if (has1)
          acc[1][nf] =
              __builtin_amdgcn_mfma_f32_16x16x32_bf16(a1, bb, acc[1][nf], 0, 0, 0);
      }
      c0a = n0a; c0b = n0b; c1a = n1a; c1b = n1b;
    }
  }

  // epilogue: D row=(lane>>4)*4+rg, col=p per frag; pack 4 q-values per us4.
#pragma unroll
  for (int s = 0; s < 2; ++s) {
    if (s == 1 && !has1) break;
    const int t = s ? t1 : t0;
#pragma unroll
    for (int rg = 0; rg < 4; ++rg) {
      const int r = t * 16 + ((lane >> 4) << 2) + rg;
      const int ty = type_f[r];
      const float* Tr = T + (size_t)ty * HID;
#pragma unroll
      for (int g = 0; g < 4; ++g) {
        us4 o;
#pragma unroll
        for (int q = 0; q < 4; ++q) {
          const int c = g * 64 + q * 16 + p;
          o[q] = f2bf(acc[s][g * 4 + q][rg] + Tr[c]);
        }
        *(us4*)(h + (size_t)r * HID + g * 64 + p * 4) = o;
      }
    }
  }
}

// ---------------- aggregate: one wave per node, us4 (8B) per lane ------------
__global__ __launch_bounds__(256) void agg_kernel(
    const u16* __restrict__ h, const int* __restrict__ csr,
    const int* __restrict__ offsets, const float* __restrict__ dinv,
    const float* __restrict__ bias, const float* __restrict__ alpha,
    float* __restrict__ out) {
  const int lane = threadIdx.x & 63;
  const int node = blockIdx.x * 4 + (threadIdx.x >> 6);
  if (node >= N_NODES) return;
  const int blk = lane >> 4, p = lane & 15;
  float bb[4], aa[4];
#pragma unroll
  for (int q = 0; q < 4; ++q) {
    const int c = blk * 64 + q * 16 + p;
    bb[q] = bias[c];
    aa[q] = alpha[c];
  }
  const us4* __restrict__ h4 = (const us4*)h;
  const float di = dinv[node];
  us4 v = h4[(size_t)node * 64 + lane];
  float acc[4];
#pragma unroll
  for (int q = 0; q < 4; ++q) acc[q] = di * bf2f(v[q]);
  const int beg = offsets[node], end = offsets[node + 1];
  int j = beg;
  for (; j + 3 < end; j += 4) {
    const int s0 = csr[j], s1 = csr[j + 1], s2 = csr[j + 2], s3 = csr[j + 3];
    const float w0 = dinv[s0], w1 = dinv[s1], w2 = dinv[s2], w3 = dinv[s3];
    const us4 v0 = h4[(size_t)s0 * 64 + lane];
    const us4 v1 = h4[(size_t)s1 * 64 + lane];
    const us4 v2 = h4[(size_t)s2 * 64 + lane];
    const us4 v3 = h4[(size_t)s3 * 64 + lane];
#pragma unroll
    for (int q = 0; q < 4; ++q) {
      acc[q] = fmaf(w0, bf2f(v0[q]), acc[q]);
      acc[q] = fmaf(w1, bf2f(v1[q]), acc[q]);
      acc[q] = fmaf(w2, bf2f(v2[q]), acc[q]);
      acc[q] = fmaf(w3, bf2f(v3[q]), acc[q]);
    }
  }
  for (; j < end; ++j) {
    const int s0 = csr[j];
    const float w0 = dinv[s0];
    const us4 v0 = h4[(size_t)s0 * 64 + lane];
#pragma unroll
    for (int q = 0; q < 4; ++q) acc[q] = fmaf(w0, bf2f(v0[q]), acc[q]);
  }
#pragma unroll
  for (int q = 0; q < 4; ++q) {
    float r = fmaf(di, acc[q], bb[q]);
    r = r > 0.f ? r : aa[q] * r;
    out[(size_t)node * HID + blk * 64 + q * 16 + p] = r;
  }
}

extern "C" void kernel_launch(void* const* d_in, const int* in_sizes, int n_in,
                              void* d_out, int out_size, void* d_ws, size_t ws_size,
                              hipStream_t stream) {
  const float* span = (const float*)d_in[0];
  const int* type_f = (const int*)d_in[1];
  const int* ei = (const int*)d_in[2];
  const float* emb = (const float*)d_in[3];
  const float* W = (const float*)d_in[4];
  const float* bias = (const float*)d_in[5];
  const float* alpha = (const float*)d_in[6];
  float* out = (float*)d_out;

  char* ws = (char*)d_ws;
  size_t off = 0;
  auto alloc = [&](size_t bytes) {
    char* p = ws + off;
    off = (off + bytes + 255) & ~(size_t)255;
    return p;
  };
  u16* h = (u16*)alloc((size_t)N_NODES * HID * 2);              // 25.6 MB (bf16)
  u16* wp = (u16*)alloc((size_t)NKB * NNF * 64 * 8 * 2);        // 393 KB
  float* T = (float*)alloc((size_t)N_TYPES * HID * 4);          // 8 KB
  int* cnt = (int*)alloc((size_t)N_NODES * 4);
  int* offsets = (int*)alloc((size_t)(N_NODES + 1) * 4);
  int* cursor = (int*)alloc((size_t)N_NODES * 4);
  float* dinv = (float*)alloc((size_t)N_NODES * 4);
  int* bsum = (int*)alloc((size_t)NRB * 4);
  int* csr = (int*)alloc((size_t)N_EDGES * 4);                  // 3.2 MB

  hipMemsetAsync(cnt, 0, (size_t)N_NODES * 4, stream);
  prep_kernel<<<104, 256, 0, stream>>>(emb, W, wp, T);
  count_kernel<<<N_EDGES / 256, 256, 0, stream>>>(ei, cnt);
  reduce_kernel<<<NRB, 256, 0, stream>>>(cnt, bsum, dinv);
  scanb_kernel<<<1, 64, 0, stream>>>(bsum, offsets);
  scanc_kernel<<<NRB, 256, 0, stream>>>(cnt, bsum, offsets, cursor);
  fill_kernel<<<N_EDGES / 256, 256, 0, stream>>>(ei, cursor, csr);
  gemm_kernel<<<256, 512, 0, stream>>>(span, wp, T, type_f, h);
  agg_kernel<<<(N_NODES + 3) / 4, 256, 0, stream>>>(h, csr, offsets, dinv, bias,
                                                    alpha, out);
}